// Round 9
// baseline (146.442 us; speedup 1.0000x reference)
//
#include <hip/hip_runtime.h>
#include <hip/hip_bf16.h>
#include <stdint.h>
#include <math.h>

#define NN 8192
#define MM 8192
#define DD 256
#define NPART ((NN / 128) * (MM / 128))  // 4096 blocks
#define LOG2E 1.44269504088896340736f
#define LN2 0.69314718055994530942f

typedef __attribute__((ext_vector_type(8))) short short8;
typedef __attribute__((ext_vector_type(4))) float float4v;
typedef __attribute__((ext_vector_type(2))) unsigned uint2v;
typedef __attribute__((ext_vector_type(4))) unsigned uint4v;
typedef __attribute__((ext_vector_type(2))) long long2v;

__device__ __forceinline__ unsigned cvt_pk_bf16(float lo, float hi) {
  unsigned r;
  asm("v_cvt_pk_bf16_f32 %0, %1, %2" : "=v"(r) : "v"(lo), "v"(hi));
  return r;
}

// f32 -> fp8 e4m3 (OCP), written in the LDS-chunk-permuted layout:
// within each 64B K-tile of a row, phys chunk c (16B) = logical 8B slots {c, c+4}
// (i.e. k in [8c,8c+8) then [32+8c,32+8c+8)). One thread = one 16B output chunk.
__global__ void convert_both_fp8(const float* __restrict__ A32,
                                 const float* __restrict__ B32,
                                 unsigned char* __restrict__ A8,
                                 unsigned char* __restrict__ B8) {
  const int nchunks = NN * DD / 16;  // per array (131072)
  const int stride = gridDim.x * blockDim.x;
  for (int idx = blockIdx.x * blockDim.x + threadIdx.x; idx < 2 * nchunks;
       idx += stride) {
    const bool isA = idx < nchunks;
    const int h = isA ? idx : idx - nchunks;
    const int row = h >> 4;
    const int t = h & 15;
    const int kt = t >> 2;
    const int c = t & 3;
    const float* src = (isA ? A32 : B32) + (size_t)row * DD + (kt << 6) + (c << 3);
    const float4v x0 = *(const float4v*)(src);
    const float4v x1 = *(const float4v*)(src + 4);
    const float4v y0 = *(const float4v*)(src + 32);
    const float4v y1 = *(const float4v*)(src + 36);
    int w0 = __builtin_amdgcn_cvt_pk_fp8_f32(x0[0], x0[1], 0, false);
    w0 = __builtin_amdgcn_cvt_pk_fp8_f32(x0[2], x0[3], w0, true);
    int w1 = __builtin_amdgcn_cvt_pk_fp8_f32(x1[0], x1[1], 0, false);
    w1 = __builtin_amdgcn_cvt_pk_fp8_f32(x1[2], x1[3], w1, true);
    int w2 = __builtin_amdgcn_cvt_pk_fp8_f32(y0[0], y0[1], 0, false);
    w2 = __builtin_amdgcn_cvt_pk_fp8_f32(y0[2], y0[3], w2, true);
    int w3 = __builtin_amdgcn_cvt_pk_fp8_f32(y1[0], y1[1], 0, false);
    w3 = __builtin_amdgcn_cvt_pk_fp8_f32(y1[2], y1[3], w3, true);
    uint4v o;
    o[0] = (unsigned)w0; o[1] = (unsigned)w1;
    o[2] = (unsigned)w2; o[3] = (unsigned)w3;
    *(uint4v*)((isA ? A8 : B8) + (size_t)h * 16) = o;
  }
}

__device__ __forceinline__ short8 pack8(float4v a0, float4v a1) {
  union { short8 s; unsigned u[4]; } r;
  r.u[0] = cvt_pk_bf16(a0[0], a0[1]);
  r.u[1] = cvt_pk_bf16(a0[2], a0[3]);
  r.u[2] = cvt_pk_bf16(a1[0], a1[1]);
  r.u[3] = cvt_pk_bf16(a1[2], a1[3]);
  return r.s;
}

// ======================= fp8 GEMM + fused loss =======================
// 128x128 tile, BK=64, 4 waves (2x2), wave 64x64 via 4x4 mfma_f32_16x16x32_fp8_fp8.
// LDS: [128 rows][64B] per operand (8KB), single-buffered, LINEAR (layout permutation
// was done at convert time). Lane (quad q, col16) reads b128 at row*64 + q*16 ->
// {kk0,kk1} fragments; banks (col16&1)*16 + q*4 + {0..3} = perfectly uniform,
// zero conflicts. No read-side address math beyond row*64 + q*16.
__global__ __launch_bounds__(256, 6) void gemm_sigloss_fp8ws(
    const unsigned char* __restrict__ A8, const unsigned char* __restrict__ B8,
    const int* __restrict__ la, const int* __restrict__ lb,
    const float* __restrict__ scale_p, const float* __restrict__ bias_p,
    float* __restrict__ pos_part, float* __restrict__ neg_part,
    unsigned* __restrict__ cnt_part) {
  __shared__ __align__(16) unsigned char As[128 * 64];
  __shared__ __align__(16) unsigned char Bs[128 * 64];
  __shared__ float redp[4], redn[4];
  __shared__ unsigned redc[4];

  const int tid = threadIdx.x;
  const int w = tid >> 6;
  const int l = tid & 63;
  // bijective XCD swizzle: 4096 % 8 == 0
  const int bid = ((blockIdx.x & 7) << 9) + (blockIdx.x >> 3);
  const int brow = (bid >> 6) << 7;
  const int bcol = (bid & 63) << 7;
  const int wrow = (w >> 1) << 6;
  const int wcol = (w & 1) << 6;
  const int col16 = l & 15;
  const int quad = l >> 4;

  float4v acc[4][4];
#pragma unroll
  for (int a = 0; a < 4; ++a)
#pragma unroll
    for (int b = 0; b < 4; ++b) acc[a][b] = (float4v){0.f, 0.f, 0.f, 0.f};

  for (int kt = 0; kt < 4; ++kt) {
    const int k0 = kt << 6;
#pragma unroll
    for (int i = 0; i < 2; ++i) {
      const int r = (i << 6) + (tid >> 2);
      __builtin_amdgcn_global_load_lds(
          (const __attribute__((address_space(1))) void*)(
              A8 + (size_t)(brow + r) * DD + k0 + ((tid & 3) << 4)),
          (__attribute__((address_space(3))) void*)(&As[(i << 12) + tid * 16]),
          16, 0, 0);
      __builtin_amdgcn_global_load_lds(
          (const __attribute__((address_space(1))) void*)(
              B8 + (size_t)(bcol + r) * DD + k0 + ((tid & 3) << 4)),
          (__attribute__((address_space(3))) void*)(&Bs[(i << 12) + tid * 16]),
          16, 0, 0);
    }
    __syncthreads();
    long2v af[4], bfv[4];
#pragma unroll
    for (int mi = 0; mi < 4; ++mi) {
      const int row = wrow + (mi << 4) + col16;
      af[mi] = *(const long2v*)(&As[row * 64 + (quad << 4)]);
    }
#pragma unroll
    for (int ni = 0; ni < 4; ++ni) {
      const int row = wcol + (ni << 4) + col16;
      bfv[ni] = *(const long2v*)(&Bs[row * 64 + (quad << 4)]);
    }
#pragma unroll
    for (int mi = 0; mi < 4; ++mi)
#pragma unroll
      for (int ni = 0; ni < 4; ++ni) {
        acc[mi][ni] = __builtin_amdgcn_mfma_f32_16x16x32_fp8_fp8(
            af[mi][0], bfv[ni][0], acc[mi][ni], 0, 0, 0);
        acc[mi][ni] = __builtin_amdgcn_mfma_f32_16x16x32_fp8_fp8(
            af[mi][1], bfv[ni][1], acc[mi][ni], 0, 0, 0);
      }
    __syncthreads();
  }

  // ---- slim fused epilogue, base-2 softplus ----
  const float s2 = (*scale_p) * LOG2E;
  const float b2 = (*bias_p) * LOG2E;
  float st = 0.f, sp = 0.f;
  int pc = 0;

  int lbv[4];
#pragma unroll
  for (int ni = 0; ni < 4; ++ni) lbv[ni] = lb[bcol + wcol + (ni << 4) + col16];

#pragma unroll
  for (int mi = 0; mi < 4; ++mi) {
#pragma unroll
    for (int r = 0; r < 4; ++r) {
      const int grow = brow + wrow + (mi << 4) + (quad << 2) + r;
      const int lav = la[grow];
#pragma unroll
      for (int ni = 0; ni < 4; ++ni) {
        const float v = fmaf(s2, acc[mi][ni][r], b2);
        const bool m = (lav == lbv[ni]);
        const float u = m ? -v : v;
        const float e = __builtin_amdgcn_exp2f(-fabsf(u));
        const float xx = fmaxf(u, 0.f) + __builtin_amdgcn_logf(1.f + e);
        st += xx;
        if (__builtin_expect(__any(m), 0)) {
          if (m) { sp += xx; ++pc; }
        }
      }
    }
  }

#pragma unroll
  for (int off = 32; off > 0; off >>= 1) {
    st += __shfl_down(st, off);
    sp += __shfl_down(sp, off);
    pc += __shfl_down(pc, off);
  }
  if (l == 0) { redp[w] = sp; redn[w] = st; redc[w] = (unsigned)pc; }
  __syncthreads();
  if (tid == 0) {
    const float tp = redp[0] + redp[1] + redp[2] + redp[3];
    const float tt = redn[0] + redn[1] + redn[2] + redn[3];
    pos_part[blockIdx.x] = LN2 * tp;
    neg_part[blockIdx.x] = LN2 * (tt - tp);
    cnt_part[blockIdx.x] = redc[0] + redc[1] + redc[2] + redc[3];
  }
}

// ============== f32 fallback: round-6 bf16-in-LDS structure ==============
__global__ __launch_bounds__(256, 3) void gemm_sigloss_f32(
    const float* __restrict__ A32, const float* __restrict__ B32,
    const int* __restrict__ la, const int* __restrict__ lb,
    const float* __restrict__ scale_p, const float* __restrict__ bias_p,
    float* __restrict__ pos_part, float* __restrict__ neg_part,
    unsigned* __restrict__ cnt_part) {
  __shared__ unsigned short As[128 * 64];
  __shared__ unsigned short Bs[128 * 64];
  __shared__ float redp[4], redn[4];
  __shared__ unsigned redc[4];

  const int tid = threadIdx.x;
  const int w = tid >> 6;
  const int l = tid & 63;
  const int bid = ((blockIdx.x & 7) << 9) + (blockIdx.x >> 3);
  const int brow = (bid >> 6) << 7;
  const int bcol = (bid & 63) << 7;
  const int wrow = (w >> 1) << 6;
  const int wcol = (w & 1) << 6;
  const int col16 = l & 15;
  const int quad = l >> 4;

  float4v acc[4][4];
#pragma unroll
  for (int a = 0; a < 4; ++a)
#pragma unroll
    for (int b = 0; b < 4; ++b) acc[a][b] = (float4v){0.f, 0.f, 0.f, 0.f};

  const int rg = l >> 3;
  const int c8 = l & 7;
  const int ksw = (c8 ^ rg) << 3;

  for (int kt = 0; kt < DD / 64; ++kt) {
    const int k0 = kt << 6;
#pragma unroll
    for (int i = 0; i < 4; ++i) {
      const int trow = (w << 5) + (i << 3) + rg;
      const float4v* pa = (const float4v*)(A32 + (size_t)(brow + trow) * DD + k0 + ksw);
      const float4v* pb = (const float4v*)(B32 + (size_t)(bcol + trow) * DD + k0 + ksw);
      const int lofs = ((w << 2) + i) << 9;
      *(short8*)((char*)As + (size_t)lofs * 2 + (size_t)l * 16) = pack8(pa[0], pa[1]);
      *(short8*)((char*)Bs + (size_t)lofs * 2 + (size_t)l * 16) = pack8(pb[0], pb[1]);
    }
    __syncthreads();
#pragma unroll
    for (int kk = 0; kk < 2; ++kk) {
      const int kb = (kk << 6) + (quad << 4);
      const int sw = (col16 & 7) << 4;
      short8 af[4], bfv[4];
#pragma unroll
      for (int mi = 0; mi < 4; ++mi) {
        const int row = wrow + (mi << 4) + col16;
        af[mi] = *(const short8*)((const char*)As + row * 128 + (kb ^ sw));
      }
#pragma unroll
      for (int ni = 0; ni < 4; ++ni) {
        const int row = wcol + (ni << 4) + col16;
        bfv[ni] = *(const short8*)((const char*)Bs + row * 128 + (kb ^ sw));
      }
#pragma unroll
      for (int mi = 0; mi < 4; ++mi)
#pragma unroll
        for (int ni = 0; ni < 4; ++ni)
          acc[mi][ni] = __builtin_amdgcn_mfma_f32_16x16x32_bf16(
              af[mi], bfv[ni], acc[mi][ni], 0, 0, 0);
    }
    __syncthreads();
  }

  const float s2 = (*scale_p) * LOG2E;
  const float b2 = (*bias_p) * LOG2E;
  float st = 0.f, sp = 0.f;
  int pc = 0;
  int lbv[4];
#pragma unroll
  for (int ni = 0; ni < 4; ++ni) lbv[ni] = lb[bcol + wcol + (ni << 4) + col16];
#pragma unroll
  for (int mi = 0; mi < 4; ++mi) {
#pragma unroll
    for (int r = 0; r < 4; ++r) {
      const int grow = brow + wrow + (mi << 4) + (quad << 2) + r;
      const int lav = la[grow];
#pragma unroll
      for (int ni = 0; ni < 4; ++ni) {
        const float v = fmaf(s2, acc[mi][ni][r], b2);
        const bool m = (lav == lbv[ni]);
        const float u = m ? -v : v;
        const float e = __builtin_amdgcn_exp2f(-fabsf(u));
        const float xx = fmaxf(u, 0.f) + __builtin_amdgcn_logf(1.f + e);
        st += xx;
        if (__builtin_expect(__any(m), 0)) {
          if (m) { sp += xx; ++pc; }
        }
      }
    }
  }
#pragma unroll
  for (int off = 32; off > 0; off >>= 1) {
    st += __shfl_down(st, off);
    sp += __shfl_down(sp, off);
    pc += __shfl_down(pc, off);
  }
  if (l == 0) { redp[w] = sp; redn[w] = st; redc[w] = (unsigned)pc; }
  __syncthreads();
  if (tid == 0) {
    const float tp = redp[0] + redp[1] + redp[2] + redp[3];
    const float tt = redn[0] + redn[1] + redn[2] + redn[3];
    pos_part[bid] = LN2 * tp;
    neg_part[bid] = LN2 * (tt - tp);
    cnt_part[bid] = redc[0] + redc[1] + redc[2] + redc[3];
  }
}

__global__ __launch_bounds__(256) void finalize_loss(
    const float* __restrict__ pos_part, const float* __restrict__ neg_part,
    const unsigned* __restrict__ cnt_part, float* __restrict__ out) {
  __shared__ float rp[4], rn[4];
  __shared__ unsigned rc[4];
  const int w = threadIdx.x >> 6;
  const int l = threadIdx.x & 63;
  float ps = 0.f, ns = 0.f;
  int pc = 0;
  for (int i = threadIdx.x; i < NPART; i += 256) {
    ps += pos_part[i];
    ns += neg_part[i];
    pc += (int)cnt_part[i];
  }
#pragma unroll
  for (int off = 32; off > 0; off >>= 1) {
    ps += __shfl_down(ps, off);
    ns += __shfl_down(ns, off);
    pc += __shfl_down(pc, off);
  }
  if (l == 0) { rp[w] = ps; rn[w] = ns; rc[w] = (unsigned)pc; }
  __syncthreads();
  if (threadIdx.x == 0) {
    double tp = (double)rp[0] + rp[1] + rp[2] + rp[3];
    double tn = (double)rn[0] + rn[1] + rn[2] + rn[3];
    long long tc = (long long)rc[0] + rc[1] + rc[2] + rc[3];
    double num_pos = (double)(tc > 1 ? tc : 1);
    long long negc = (long long)NN * MM - tc;
    double num_neg = (double)(negc > 1 ? negc : 1);
    out[0] = (float)(tp / num_pos + tn / num_neg * (double)(NN - 1));
  }
}

extern "C" void kernel_launch(void* const* d_in, const int* in_sizes, int n_in,
                              void* d_out, int out_size, void* d_ws, size_t ws_size,
                              hipStream_t stream) {
  const float* A32 = (const float*)d_in[0];
  const float* B32 = (const float*)d_in[1];
  const int* la = (const int*)d_in[2];
  const int* lb = (const int*)d_in[3];
  const float* scale_p = (const float*)d_in[4];
  const float* bias_p = (const float*)d_in[5];
  float* out = (float*)d_out;

  char* ws = (char*)d_ws;
  float* pos_part = (float*)ws;                       // 4096 f32
  float* neg_part = pos_part + NPART;                 // 4096 f32
  unsigned* cnt_part = (unsigned*)(neg_part + NPART); // 4096 u32
  unsigned char* A8 = (unsigned char*)(ws + 65536);
  unsigned char* B8 = A8 + (size_t)NN * DD;

  const size_t need = 65536 + 2ull * (size_t)NN * DD;
  const bool use8 = (ws_size >= need);

  if (use8) {
    convert_both_fp8<<<1024, 256, 0, stream>>>(A32, B32, A8, B8);
    gemm_sigloss_fp8ws<<<NPART, 256, 0, stream>>>(A8, B8, la, lb, scale_p,
                                                  bias_p, pos_part, neg_part,
                                                  cnt_part);
  } else {
    gemm_sigloss_f32<<<NPART, 256, 0, stream>>>(A32, B32, la, lb, scale_p,
                                                bias_p, pos_part, neg_part,
                                                cnt_part);
  }
  finalize_loss<<<1, 256, 0, stream>>>(pos_part, neg_part, cnt_part, out);
}

// Round 10
// 51.344 us; speedup vs baseline: 2.8522x; 2.8522x over previous
//
#include <hip/hip_runtime.h>
#include <hip/hip_bf16.h>
#include <stdint.h>
#include <math.h>

#define NN 8192
#define MM 8192
#define DD 256
#define NPART ((NN / 128) * (MM / 128))  // 4096 blocks
#define LOG2E 1.44269504088896340736f
#define LN2 0.69314718055994530942f

typedef __attribute__((ext_vector_type(8))) short short8;
typedef __attribute__((ext_vector_type(4))) float float4v;
typedef __attribute__((ext_vector_type(2))) unsigned uint2v;
typedef __attribute__((ext_vector_type(4))) unsigned uint4v;
typedef __attribute__((ext_vector_type(2))) long long2v;

__device__ __forceinline__ unsigned cvt_pk_bf16(float lo, float hi) {
  unsigned r;
  asm("v_cvt_pk_bf16_f32 %0, %1, %2" : "=v"(r) : "v"(lo), "v"(hi));
  return r;
}

// f32 -> fp8 e4m3 (OCP), written in the LDS-chunk-permuted layout:
// within each 64B K-tile of a row, phys chunk c (16B) = logical 8B slots {c, c+4}
// (i.e. k in [8c,8c+8) then [32+8c,32+8c+8)). One thread = one 16B output chunk.
__global__ void convert_both_fp8(const float* __restrict__ A32,
                                 const float* __restrict__ B32,
                                 unsigned char* __restrict__ A8,
                                 unsigned char* __restrict__ B8) {
  const int nchunks = NN * DD / 16;  // per array (131072)
  const int stride = gridDim.x * blockDim.x;
  for (int idx = blockIdx.x * blockDim.x + threadIdx.x; idx < 2 * nchunks;
       idx += stride) {
    const bool isA = idx < nchunks;
    const int h = isA ? idx : idx - nchunks;
    const int row = h >> 4;
    const int t = h & 15;
    const int kt = t >> 2;
    const int c = t & 3;
    const float* src = (isA ? A32 : B32) + (size_t)row * DD + (kt << 6) + (c << 3);
    const float4v x0 = *(const float4v*)(src);
    const float4v x1 = *(const float4v*)(src + 4);
    const float4v y0 = *(const float4v*)(src + 32);
    const float4v y1 = *(const float4v*)(src + 36);
    int w0 = __builtin_amdgcn_cvt_pk_fp8_f32(x0[0], x0[1], 0, false);
    w0 = __builtin_amdgcn_cvt_pk_fp8_f32(x0[2], x0[3], w0, true);
    int w1 = __builtin_amdgcn_cvt_pk_fp8_f32(x1[0], x1[1], 0, false);
    w1 = __builtin_amdgcn_cvt_pk_fp8_f32(x1[2], x1[3], w1, true);
    int w2 = __builtin_amdgcn_cvt_pk_fp8_f32(y0[0], y0[1], 0, false);
    w2 = __builtin_amdgcn_cvt_pk_fp8_f32(y0[2], y0[3], w2, true);
    int w3 = __builtin_amdgcn_cvt_pk_fp8_f32(y1[0], y1[1], 0, false);
    w3 = __builtin_amdgcn_cvt_pk_fp8_f32(y1[2], y1[3], w3, true);
    uint4v o;
    o[0] = (unsigned)w0; o[1] = (unsigned)w1;
    o[2] = (unsigned)w2; o[3] = (unsigned)w3;
    *(uint4v*)((isA ? A8 : B8) + (size_t)h * 16) = o;
  }
}

__device__ __forceinline__ short8 pack8(float4v a0, float4v a1) {
  union { short8 s; unsigned u[4]; } r;
  r.u[0] = cvt_pk_bf16(a0[0], a0[1]);
  r.u[1] = cvt_pk_bf16(a0[2], a0[3]);
  r.u[2] = cvt_pk_bf16(a1[0], a1[1]);
  r.u[3] = cvt_pk_bf16(a1[2], a1[3]);
  return r.s;
}

// ======================= fp8 GEMM + fused loss =======================
// 128x128 tile, BK=64, 4 waves (2x2), wave 64x64 via 4x4 mfma_f32_16x16x32_fp8_fp8.
// LDS: [128 rows][64B] per operand (8KB), single-buffered, LINEAR (layout permutation
// done at convert time). Lane (quad q, col16) reads b128 at row*64 + q*16 ->
// {kk0,kk1} fragments. __launch_bounds__(256,4): 128 VGPR cap -> NO SPILL
// (round-9 lesson: (256,6) capped at ~85 and spilled acc to scratch).
__global__ __launch_bounds__(256, 4) void gemm_sigloss_fp8ws(
    const unsigned char* __restrict__ A8, const unsigned char* __restrict__ B8,
    const int* __restrict__ la, const int* __restrict__ lb,
    const float* __restrict__ scale_p, const float* __restrict__ bias_p,
    float* __restrict__ pos_part, float* __restrict__ neg_part,
    unsigned* __restrict__ cnt_part) {
  __shared__ __align__(16) unsigned char As[128 * 64];
  __shared__ __align__(16) unsigned char Bs[128 * 64];
  __shared__ float redp[4], redn[4];
  __shared__ unsigned redc[4];

  const int tid = threadIdx.x;
  const int w = tid >> 6;
  const int l = tid & 63;
  // bijective XCD swizzle: 4096 % 8 == 0
  const int bid = ((blockIdx.x & 7) << 9) + (blockIdx.x >> 3);
  const int brow = (bid >> 6) << 7;
  const int bcol = (bid & 63) << 7;
  const int wrow = (w >> 1) << 6;
  const int wcol = (w & 1) << 6;
  const int col16 = l & 15;
  const int quad = l >> 4;

  float4v acc[4][4];
#pragma unroll
  for (int a = 0; a < 4; ++a)
#pragma unroll
    for (int b = 0; b < 4; ++b) acc[a][b] = (float4v){0.f, 0.f, 0.f, 0.f};

  for (int kt = 0; kt < 4; ++kt) {
    const int k0 = kt << 6;
#pragma unroll
    for (int i = 0; i < 2; ++i) {
      const int r = (i << 6) + (tid >> 2);
      __builtin_amdgcn_global_load_lds(
          (const __attribute__((address_space(1))) void*)(
              A8 + (size_t)(brow + r) * DD + k0 + ((tid & 3) << 4)),
          (__attribute__((address_space(3))) void*)(&As[(i << 12) + tid * 16]),
          16, 0, 0);
      __builtin_amdgcn_global_load_lds(
          (const __attribute__((address_space(1))) void*)(
              B8 + (size_t)(bcol + r) * DD + k0 + ((tid & 3) << 4)),
          (__attribute__((address_space(3))) void*)(&Bs[(i << 12) + tid * 16]),
          16, 0, 0);
    }
    __syncthreads();
    long2v af[4], bfv[4];
#pragma unroll
    for (int mi = 0; mi < 4; ++mi) {
      const int row = wrow + (mi << 4) + col16;
      af[mi] = *(const long2v*)(&As[row * 64 + (quad << 4)]);
    }
#pragma unroll
    for (int ni = 0; ni < 4; ++ni) {
      const int row = wcol + (ni << 4) + col16;
      bfv[ni] = *(const long2v*)(&Bs[row * 64 + (quad << 4)]);
    }
#pragma unroll
    for (int mi = 0; mi < 4; ++mi)
#pragma unroll
      for (int ni = 0; ni < 4; ++ni) {
        acc[mi][ni] = __builtin_amdgcn_mfma_f32_16x16x32_fp8_fp8(
            af[mi][0], bfv[ni][0], acc[mi][ni], 0, 0, 0);
        acc[mi][ni] = __builtin_amdgcn_mfma_f32_16x16x32_fp8_fp8(
            af[mi][1], bfv[ni][1], acc[mi][ni], 0, 0, 0);
      }
    __syncthreads();
  }

  // ---- slim fused epilogue, base-2 softplus ----
  const float s2 = (*scale_p) * LOG2E;
  const float b2 = (*bias_p) * LOG2E;
  float st = 0.f, sp = 0.f;
  int pc = 0;

  int lbv[4];
#pragma unroll
  for (int ni = 0; ni < 4; ++ni) lbv[ni] = lb[bcol + wcol + (ni << 4) + col16];

#pragma unroll
  for (int mi = 0; mi < 4; ++mi) {
#pragma unroll
    for (int r = 0; r < 4; ++r) {
      const int grow = brow + wrow + (mi << 4) + (quad << 2) + r;
      const int lav = la[grow];
#pragma unroll
      for (int ni = 0; ni < 4; ++ni) {
        const float v = fmaf(s2, acc[mi][ni][r], b2);
        const bool m = (lav == lbv[ni]);
        const float u = m ? -v : v;
        const float e = __builtin_amdgcn_exp2f(-fabsf(u));
        const float xx = fmaxf(u, 0.f) + __builtin_amdgcn_logf(1.f + e);
        st += xx;
        if (__builtin_expect(__any(m), 0)) {
          if (m) { sp += xx; ++pc; }
        }
      }
    }
  }

#pragma unroll
  for (int off = 32; off > 0; off >>= 1) {
    st += __shfl_down(st, off);
    sp += __shfl_down(sp, off);
    pc += __shfl_down(pc, off);
  }
  if (l == 0) { redp[w] = sp; redn[w] = st; redc[w] = (unsigned)pc; }
  __syncthreads();
  if (tid == 0) {
    const float tp = redp[0] + redp[1] + redp[2] + redp[3];
    const float tt = redn[0] + redn[1] + redn[2] + redn[3];
    pos_part[blockIdx.x] = LN2 * tp;
    neg_part[blockIdx.x] = LN2 * (tt - tp);
    cnt_part[blockIdx.x] = redc[0] + redc[1] + redc[2] + redc[3];
  }
}

// ============== f32 fallback: round-6 bf16-in-LDS structure ==============
__global__ __launch_bounds__(256, 3) void gemm_sigloss_f32(
    const float* __restrict__ A32, const float* __restrict__ B32,
    const int* __restrict__ la, const int* __restrict__ lb,
    const float* __restrict__ scale_p, const float* __restrict__ bias_p,
    float* __restrict__ pos_part, float* __restrict__ neg_part,
    unsigned* __restrict__ cnt_part) {
  __shared__ unsigned short As[128 * 64];
  __shared__ unsigned short Bs[128 * 64];
  __shared__ float redp[4], redn[4];
  __shared__ unsigned redc[4];

  const int tid = threadIdx.x;
  const int w = tid >> 6;
  const int l = tid & 63;
  const int bid = ((blockIdx.x & 7) << 9) + (blockIdx.x >> 3);
  const int brow = (bid >> 6) << 7;
  const int bcol = (bid & 63) << 7;
  const int wrow = (w >> 1) << 6;
  const int wcol = (w & 1) << 6;
  const int col16 = l & 15;
  const int quad = l >> 4;

  float4v acc[4][4];
#pragma unroll
  for (int a = 0; a < 4; ++a)
#pragma unroll
    for (int b = 0; b < 4; ++b) acc[a][b] = (float4v){0.f, 0.f, 0.f, 0.f};

  const int rg = l >> 3;
  const int c8 = l & 7;
  const int ksw = (c8 ^ rg) << 3;

  for (int kt = 0; kt < DD / 64; ++kt) {
    const int k0 = kt << 6;
#pragma unroll
    for (int i = 0; i < 4; ++i) {
      const int trow = (w << 5) + (i << 3) + rg;
      const float4v* pa = (const float4v*)(A32 + (size_t)(brow + trow) * DD + k0 + ksw);
      const float4v* pb = (const float4v*)(B32 + (size_t)(bcol + trow) * DD + k0 + ksw);
      const int lofs = ((w << 2) + i) << 9;
      *(short8*)((char*)As + (size_t)lofs * 2 + (size_t)l * 16) = pack8(pa[0], pa[1]);
      *(short8*)((char*)Bs + (size_t)lofs * 2 + (size_t)l * 16) = pack8(pb[0], pb[1]);
    }
    __syncthreads();
#pragma unroll
    for (int kk = 0; kk < 2; ++kk) {
      const int kb = (kk << 6) + (quad << 4);
      const int sw = (col16 & 7) << 4;
      short8 af[4], bfv[4];
#pragma unroll
      for (int mi = 0; mi < 4; ++mi) {
        const int row = wrow + (mi << 4) + col16;
        af[mi] = *(const short8*)((const char*)As + row * 128 + (kb ^ sw));
      }
#pragma unroll
      for (int ni = 0; ni < 4; ++ni) {
        const int row = wcol + (ni << 4) + col16;
        bfv[ni] = *(const short8*)((const char*)Bs + row * 128 + (kb ^ sw));
      }
#pragma unroll
      for (int mi = 0; mi < 4; ++mi)
#pragma unroll
        for (int ni = 0; ni < 4; ++ni)
          acc[mi][ni] = __builtin_amdgcn_mfma_f32_16x16x32_bf16(
              af[mi], bfv[ni], acc[mi][ni], 0, 0, 0);
    }
    __syncthreads();
  }

  const float s2 = (*scale_p) * LOG2E;
  const float b2 = (*bias_p) * LOG2E;
  float st = 0.f, sp = 0.f;
  int pc = 0;
  int lbv[4];
#pragma unroll
  for (int ni = 0; ni < 4; ++ni) lbv[ni] = lb[bcol + wcol + (ni << 4) + col16];
#pragma unroll
  for (int mi = 0; mi < 4; ++mi) {
#pragma unroll
    for (int r = 0; r < 4; ++r) {
      const int grow = brow + wrow + (mi << 4) + (quad << 2) + r;
      const int lav = la[grow];
#pragma unroll
      for (int ni = 0; ni < 4; ++ni) {
        const float v = fmaf(s2, acc[mi][ni][r], b2);
        const bool m = (lav == lbv[ni]);
        const float u = m ? -v : v;
        const float e = __builtin_amdgcn_exp2f(-fabsf(u));
        const float xx = fmaxf(u, 0.f) + __builtin_amdgcn_logf(1.f + e);
        st += xx;
        if (__builtin_expect(__any(m), 0)) {
          if (m) { sp += xx; ++pc; }
        }
      }
    }
  }
#pragma unroll
  for (int off = 32; off > 0; off >>= 1) {
    st += __shfl_down(st, off);
    sp += __shfl_down(sp, off);
    pc += __shfl_down(pc, off);
  }
  if (l == 0) { redp[w] = sp; redn[w] = st; redc[w] = (unsigned)pc; }
  __syncthreads();
  if (tid == 0) {
    const float tp = redp[0] + redp[1] + redp[2] + redp[3];
    const float tt = redn[0] + redn[1] + redn[2] + redn[3];
    pos_part[bid] = LN2 * tp;
    neg_part[bid] = LN2 * (tt - tp);
    cnt_part[bid] = redc[0] + redc[1] + redc[2] + redc[3];
  }
}

__global__ __launch_bounds__(256) void finalize_loss(
    const float* __restrict__ pos_part, const float* __restrict__ neg_part,
    const unsigned* __restrict__ cnt_part, float* __restrict__ out) {
  __shared__ float rp[4], rn[4];
  __shared__ unsigned rc[4];
  const int w = threadIdx.x >> 6;
  const int l = threadIdx.x & 63;
  float ps = 0.f, ns = 0.f;
  int pc = 0;
  for (int i = threadIdx.x; i < NPART; i += 256) {
    ps += pos_part[i];
    ns += neg_part[i];
    pc += (int)cnt_part[i];
  }
#pragma unroll
  for (int off = 32; off > 0; off >>= 1) {
    ps += __shfl_down(ps, off);
    ns += __shfl_down(ns, off);
    pc += __shfl_down(pc, off);
  }
  if (l == 0) { rp[w] = ps; rn[w] = ns; rc[w] = (unsigned)pc; }
  __syncthreads();
  if (threadIdx.x == 0) {
    double tp = (double)rp[0] + rp[1] + rp[2] + rp[3];
    double tn = (double)rn[0] + rn[1] + rn[2] + rn[3];
    long long tc = (long long)rc[0] + rc[1] + rc[2] + rc[3];
    double num_pos = (double)(tc > 1 ? tc : 1);
    long long negc = (long long)NN * MM - tc;
    double num_neg = (double)(negc > 1 ? negc : 1);
    out[0] = (float)(tp / num_pos + tn / num_neg * (double)(NN - 1));
  }
}

extern "C" void kernel_launch(void* const* d_in, const int* in_sizes, int n_in,
                              void* d_out, int out_size, void* d_ws, size_t ws_size,
                              hipStream_t stream) {
  const float* A32 = (const float*)d_in[0];
  const float* B32 = (const float*)d_in[1];
  const int* la = (const int*)d_in[2];
  const int* lb = (const int*)d_in[3];
  const float* scale_p = (const float*)d_in[4];
  const float* bias_p = (const float*)d_in[5];
  float* out = (float*)d_out;

  char* ws = (char*)d_ws;
  float* pos_part = (float*)ws;                       // 4096 f32
  float* neg_part = pos_part + NPART;                 // 4096 f32
  unsigned* cnt_part = (unsigned*)(neg_part + NPART); // 4096 u32
  unsigned char* A8 = (unsigned char*)(ws + 65536);
  unsigned char* B8 = A8 + (size_t)NN * DD;

  const size_t need = 65536 + 2ull * (size_t)NN * DD;
  const bool use8 = (ws_size >= need);

  if (use8) {
    convert_both_fp8<<<1024, 256, 0, stream>>>(A32, B32, A8, B8);
    gemm_sigloss_fp8ws<<<NPART, 256, 0, stream>>>(A8, B8, la, lb, scale_p,
                                                  bias_p, pos_part, neg_part,
                                                  cnt_part);
  } else {
    gemm_sigloss_f32<<<NPART, 256, 0, stream>>>(A32, B32, la, lb, scale_p,
                                                bias_p, pos_part, neg_part,
                                                cnt_part);
  }
  finalize_loss<<<1, 256, 0, stream>>>(pos_part, neg_part, cnt_part, out);
}